// Round 11
// baseline (179.588 us; speedup 1.0000x reference)
//
#include <hip/hip_runtime.h>

// Fused double-softmax attention, fp32 in/out, f16 MFMA for QK^T and PV.
// B=4 H=8 S=1024 D=64. Outputs: context [B,H,S,D] then attn [B,H,S,S].
// R11 (= R10 with exp2f fix): explicit ILP — software-pipelined K/V fragment
// loads, batched register loads in Phase B, exp2 folding.
typedef _Float16 f16;
typedef _Float16 f16x8 __attribute__((ext_vector_type(8)));
typedef _Float16 f16x4 __attribute__((ext_vector_type(4)));
typedef float f32x4 __attribute__((ext_vector_type(4)));

constexpr int B_ = 4, H_ = 8, S_ = 1024, D_ = 64;
constexpr int BQ = 16;        // q rows per block
constexpr int NT = 512;       // 8 waves
constexpr int KC = 128;       // k per chunk (one 16-col tile per wave)
constexpr int QH_LD = 72;     // Qh row stride in f16
constexpr int SC_LD = 1032;   // sch row stride in f16
constexpr float LOG2E = 1.44269504f;

__device__ __forceinline__ float wred(float v) {
#pragma unroll
  for (int off = 32; off > 0; off >>= 1) v += __shfl_xor(v, off);
  return v;
}

__global__ __launch_bounds__(NT)
void fused_attn(const float* __restrict__ Q, const float* __restrict__ K,
                const float* __restrict__ V, const int* __restrict__ mask,
                const float* __restrict__ adj, const float* __restrict__ dist,
                const float* __restrict__ cw, const float* __restrict__ cb,
                float* __restrict__ outC, float* __restrict__ outA)
{
  __shared__ __align__(16) f16 Qh[BQ * QH_LD];     // 2.3 KB
  __shared__ __align__(16) f16 sch[BQ * SC_LD];    // 33.0 KB
  __shared__ __align__(16) float fscr[NT * 4];     // 8 KB
  __shared__ float rs1w[8][16];
  __shared__ float rinv2[BQ];

  const int tid = threadIdx.x;
  // bijective XCD swizzle: 2048 blocks = 8 XCDs x 256 (4 heads per XCD)
  const int sw = (blockIdx.x & 7) * 256 + (blockIdx.x >> 3);
  const int qt = sw & 63;
  const int bh = sw >> 6;
  const int q0 = qt * BQ;
  const int wv = tid >> 6;    // wave 0..7
  const int ln = tid & 63;
  const int lg = ln >> 4;     // lane group 0..3
  const int li = ln & 15;

  const float* Qp = Q + ((size_t)bh * S_ + q0) * D_;
  const float* Kp = K + (size_t)bh * S_ * D_;
  const float* Vp = V + (size_t)bh * S_ * D_;
  const size_t rb = ((size_t)bh * S_ + q0) * S_;

  // stage Q tile -> f16
  if (tid < 256) {
    const int q = tid >> 4, c4 = (tid & 15) << 2;
    float4 v = *(const float4*)(Qp + q * D_ + c4);
    f16* d = &Qh[q * QH_LD + c4];
    d[0] = (f16)v.x; d[1] = (f16)v.y; d[2] = (f16)v.z; d[3] = (f16)v.w;
  }
  const float w0 = cw[0], w1 = cw[1], w2 = cw[2], bb = cb[0];
  __syncthreads();                                  // (1)

  // hoist Q fragments (A operand; lane li = q-row li, k = s*32 + lg*8)
  f16x8 aq0 = *(const f16x8*)&Qh[li * QH_LD + 0 * 32 + lg * 8];
  f16x8 aq1 = *(const f16x8*)&Qh[li * QH_LD + 1 * 32 + lg * 8];

  // ===== Phase A: UNMASKED e = exp(QK^T/8), pipelined K fragment loads =======
  const int n0 = wv * 16;
  float rs[4] = {0.f, 0.f, 0.f, 0.f};
  float4 ka, kb, kc2, kd;
  {
    const float* Kr = Kp + (size_t)(n0 + li) * D_ + lg * 8;
    ka = *(const float4*)(Kr + 0);  kb = *(const float4*)(Kr + 4);
    kc2 = *(const float4*)(Kr + 32); kd = *(const float4*)(Kr + 36);
  }
  for (int c = 0; c < 8; ++c) {
    // issue next chunk's loads before consuming current regs
    const int cn = (c + 1) & 7;
    const float* Krn = Kp + (size_t)(cn * KC + n0 + li) * D_ + lg * 8;
    const float4 na = *(const float4*)(Krn + 0);
    const float4 nb = *(const float4*)(Krn + 4);
    const float4 nc = *(const float4*)(Krn + 32);
    const float4 nd = *(const float4*)(Krn + 36);
    f16x8 b0, b1;
    b0[0] = (f16)ka.x; b0[1] = (f16)ka.y; b0[2] = (f16)ka.z; b0[3] = (f16)ka.w;
    b0[4] = (f16)kb.x; b0[5] = (f16)kb.y; b0[6] = (f16)kb.z; b0[7] = (f16)kb.w;
    b1[0] = (f16)kc2.x; b1[1] = (f16)kc2.y; b1[2] = (f16)kc2.z; b1[3] = (f16)kc2.w;
    b1[4] = (f16)kd.x; b1[5] = (f16)kd.y; b1[6] = (f16)kd.z; b1[7] = (f16)kd.w;
    f32x4 acc = {0.f, 0.f, 0.f, 0.f};
    acc = __builtin_amdgcn_mfma_f32_16x16x32_f16(aq0, b0, acc, 0, 0, 0);
    acc = __builtin_amdgcn_mfma_f32_16x16x32_f16(aq1, b1, acc, 0, 0, 0);
    const int kg = c * KC + n0 + li;
#pragma unroll
    for (int r = 0; r < 4; ++r) {            // D[m][n]: m=lg*4+r, n=li
      const int m = lg * 4 + r;
      const f16 ef = (f16)exp2f(acc[r] * (0.125f * LOG2E));
      sch[m * SC_LD + kg] = ef;
      rs[r] += (float)ef;                    // rounded full-row sum
    }
    ka = na; kb = nb; kc2 = nc; kd = nd;
  }
#pragma unroll
  for (int r = 0; r < 4; ++r) {              // reduce over 16 lanes per group
    rs[r] += __shfl_xor(rs[r], 1); rs[r] += __shfl_xor(rs[r], 2);
    rs[r] += __shfl_xor(rs[r], 4); rs[r] += __shfl_xor(rs[r], 8);
  }
  if (li == 0) {
#pragma unroll
    for (int r = 0; r < 4; ++r) rs1w[wv][lg * 4 + r] = rs[r];
  }
  __syncthreads();                                  // (2) sch + rs1w visible

  // ===== Phase B: mask fold + conv-softmax; wave -> rows 2wv, 2wv+1 ==========
#pragma unroll
  for (int rr = 0; rr < 2; ++rr) {
    const int q = 2 * wv + rr;
    const size_t base = rb + (size_t)q * S_;
    const int k0 = ln * 4;
    // batched loads: all 12 global + 4 LDS issued before any use
    const int4 mv0 = *(const int4*)(mask + base + k0 + 0);
    const int4 mv1 = *(const int4*)(mask + base + k0 + 256);
    const int4 mv2 = *(const int4*)(mask + base + k0 + 512);
    const int4 mv3 = *(const int4*)(mask + base + k0 + 768);
    const float4 dv0 = *(const float4*)(dist + base + k0 + 0);
    const float4 dv1 = *(const float4*)(dist + base + k0 + 256);
    const float4 dv2 = *(const float4*)(dist + base + k0 + 512);
    const float4 dv3 = *(const float4*)(dist + base + k0 + 768);
    const float4 av0 = *(const float4*)(adj + base + k0 + 0);
    const float4 av1 = *(const float4*)(adj + base + k0 + 256);
    const float4 av2 = *(const float4*)(adj + base + k0 + 512);
    const float4 av3 = *(const float4*)(adj + base + k0 + 768);
    const f16x4 ef0 = *(const f16x4*)&sch[q * SC_LD + k0 + 0];
    const f16x4 ef1 = *(const f16x4*)&sch[q * SC_LD + k0 + 256];
    const f16x4 ef2 = *(const f16x4*)&sch[q * SC_LD + k0 + 512];
    const f16x4 ef3 = *(const f16x4*)&sch[q * SC_LD + k0 + 768];
    // denominator correction from masked entries
    float corr =
        (mv0.x ? (float)ef0[0] : 0.f) + (mv0.y ? (float)ef0[1] : 0.f) +
        (mv0.z ? (float)ef0[2] : 0.f) + (mv0.w ? (float)ef0[3] : 0.f) +
        (mv1.x ? (float)ef1[0] : 0.f) + (mv1.y ? (float)ef1[1] : 0.f) +
        (mv1.z ? (float)ef1[2] : 0.f) + (mv1.w ? (float)ef1[3] : 0.f) +
        (mv2.x ? (float)ef2[0] : 0.f) + (mv2.y ? (float)ef2[1] : 0.f) +
        (mv2.z ? (float)ef2[2] : 0.f) + (mv2.w ? (float)ef2[3] : 0.f) +
        (mv3.x ? (float)ef3[0] : 0.f) + (mv3.y ? (float)ef3[1] : 0.f) +
        (mv3.z ? (float)ef3[2] : 0.f) + (mv3.w ? (float)ef3[3] : 0.f);
    float tq = 0.f;
#pragma unroll
    for (int w = 0; w < 8; ++w) tq += rs1w[w][q];   // uniform broadcast reads
    corr = wred(corr);
    const float i1 = 1.f / (tq - corr);
    const float W0 = w0 * i1 * LOG2E, W1 = w1 * LOG2E, W2 = w2 * LOG2E;
    const float BBL = bb * LOG2E;
    f16x4 af0, af1, af2, af3;
    float s2 = 0.f;
#define CSM(AF, MV, DV, AV, EF)                                               \
    {                                                                         \
      const float t0 = fmaf(W0, (float)EF[0], fmaf(W1, DV.x, fmaf(W2, AV.x, BBL))); \
      const float t1 = fmaf(W0, (float)EF[1], fmaf(W1, DV.y, fmaf(W2, AV.y, BBL))); \
      const float t2 = fmaf(W0, (float)EF[2], fmaf(W1, DV.z, fmaf(W2, AV.z, BBL))); \
      const float t3 = fmaf(W0, (float)EF[3], fmaf(W1, DV.w, fmaf(W2, AV.w, BBL))); \
      const float a0 = MV.x ? 0.f : exp2f(t0);                                \
      const float a1 = MV.y ? 0.f : exp2f(t1);                                \
      const float a2 = MV.z ? 0.f : exp2f(t2);                                \
      const float a3 = MV.w ? 0.f : exp2f(t3);                                \
      AF[0] = (f16)a0; AF[1] = (f16)a1; AF[2] = (f16)a2; AF[3] = (f16)a3;     \
      s2 += a0 + a1 + a2 + a3;                                                \
    }
    CSM(af0, mv0, dv0, av0, ef0)
    CSM(af1, mv1, dv1, av1, ef1)
    CSM(af2, mv2, dv2, av2, ef2)
    CSM(af3, mv3, dv3, av3, ef3)
#undef CSM
    *(f16x4*)&sch[q * SC_LD + k0 + 0]   = af0;
    *(f16x4*)&sch[q * SC_LD + k0 + 256] = af1;
    *(f16x4*)&sch[q * SC_LD + k0 + 512] = af2;
    *(f16x4*)&sch[q * SC_LD + k0 + 768] = af3;
    s2 = wred(s2);
    const float i2 = 1.f / s2;
    if (ln == 0) rinv2[q] = i2;
    float4 o;
    o = make_float4((float)af0[0] * i2, (float)af0[1] * i2,
                    (float)af0[2] * i2, (float)af0[3] * i2);
    *(float4*)(outA + base + k0 + 0) = o;
    o = make_float4((float)af1[0] * i2, (float)af1[1] * i2,
                    (float)af1[2] * i2, (float)af1[3] * i2);
    *(float4*)(outA + base + k0 + 256) = o;
    o = make_float4((float)af2[0] * i2, (float)af2[1] * i2,
                    (float)af2[2] * i2, (float)af2[3] * i2);
    *(float4*)(outA + base + k0 + 512) = o;
    o = make_float4((float)af3[0] * i2, (float)af3[1] * i2,
                    (float)af3[2] * i2, (float)af3[3] * i2);
    *(float4*)(outA + base + k0 + 768) = o;
  }
  __syncthreads();                                  // (3) sch aw-values visible

  // ===== Phase C: ctx = P(f16) x V(f16); pipelined V^T fragment loads ========
  const int ntile = wv >> 1;
  const int spair = (wv & 1) * 2;
  const int d0 = ntile * 16 + li;
  f32x4 cacc = {0.f, 0.f, 0.f, 0.f};
  float v0, v1, v2, v3, v4, v5, v6, v7;
  {
    const float* vp = Vp + (size_t)(spair * 32 + lg * 8) * D_ + d0;
    v0 = vp[0 * D_]; v1 = vp[1 * D_]; v2 = vp[2 * D_]; v3 = vp[3 * D_];
    v4 = vp[4 * D_]; v5 = vp[5 * D_]; v6 = vp[6 * D_]; v7 = vp[7 * D_];
  }
#pragma unroll
  for (int t = 0; t < 16; ++t) {
    const int tn = (t + 1) & 15;
    const int cn = tn >> 1, un = tn & 1;
    const float* vn = Vp + (size_t)(cn * KC + (spair + un) * 32 + lg * 8) * D_ + d0;
    const float n0v = vn[0 * D_], n1v = vn[1 * D_], n2v = vn[2 * D_], n3v = vn[3 * D_];
    const float n4v = vn[4 * D_], n5v = vn[5 * D_], n6v = vn[6 * D_], n7v = vn[7 * D_];
    f16x8 bfr;
    bfr[0] = (f16)v0; bfr[1] = (f16)v1; bfr[2] = (f16)v2; bfr[3] = (f16)v3;
    bfr[4] = (f16)v4; bfr[5] = (f16)v5; bfr[6] = (f16)v6; bfr[7] = (f16)v7;
    const int c = t >> 1, u = t & 1;
    f16x8 a = *(const f16x8*)&sch[li * SC_LD + c * KC + (spair + u) * 32 + lg * 8];
    cacc = __builtin_amdgcn_mfma_f32_16x16x32_f16(a, bfr, cacc, 0, 0, 0);
    v0 = n0v; v1 = n1v; v2 = n2v; v3 = n3v;
    v4 = n4v; v5 = n5v; v6 = n6v; v7 = n7v;
  }
  *(f32x4*)&fscr[tid * 4] = cacc;
  __syncthreads();                                  // (4)
  if (tid < 256) {                    // combine wave pairs, scale, write ctx
    const int t = tid >> 6, l2 = tid & 63;
    const int g2 = l2 >> 4, n = l2 & 15;
    f32x4 p  = *(const f32x4*)&fscr[((2 * t) * 64 + l2) * 4];
    f32x4 p2 = *(const f32x4*)&fscr[((2 * t + 1) * 64 + l2) * 4];
#pragma unroll
    for (int r = 0; r < 4; ++r) {
      const int m = g2 * 4 + r;
      outC[((size_t)bh * S_ + q0 + m) * D_ + t * 16 + n] = (p[r] + p2[r]) * rinv2[m];
    }
  }
}

extern "C" void kernel_launch(void* const* d_in, const int* in_sizes, int n_in,
                              void* d_out, int out_size, void* d_ws, size_t ws_size,
                              hipStream_t stream) {
  const float* Q    = (const float*)d_in[0];
  const float* K    = (const float*)d_in[1];
  const float* V    = (const float*)d_in[2];
  const int*   mask = (const int*)  d_in[3];
  const float* adj  = (const float*)d_in[4];
  const float* dist = (const float*)d_in[5];
  const float* cw   = (const float*)d_in[6];
  const float* cb   = (const float*)d_in[7];

  float* outC = (float*)d_out;                                   // [B,H,S,D]
  float* outA = outC + (size_t)B_ * H_ * S_ * D_;                // [B,H,S,S]

  fused_attn<<<dim3(B_ * H_ * (S_ / BQ)), NT, 0, stream>>>(
      Q, K, V, mask, adj, dist, cw, cb, outC, outA);
}

// Round 12
// 171.575 us; speedup vs baseline: 1.0467x; 1.0467x over previous
//
#include <hip/hip_runtime.h>

// Fused double-softmax attention, fp32 in/out, f16 MFMA for QK^T and PV.
// B=4 H=8 S=1024 D=64. Outputs: context [B,H,S,D] then attn [B,H,S,S].
// R12: R9 structure + (a) Phase-C scratch aliased onto sch (LDS 44.5->36.4 KB,
// 4 blocks/CU), (b) sched_barrier(0)-pinned load batch in Phase B,
// (c) inline row-sum (one fewer barrier), exp2f constant folding.
typedef _Float16 f16;
typedef _Float16 f16x8 __attribute__((ext_vector_type(8)));
typedef _Float16 f16x4 __attribute__((ext_vector_type(4)));
typedef float f32x4 __attribute__((ext_vector_type(4)));

constexpr int B_ = 4, H_ = 8, S_ = 1024, D_ = 64;
constexpr int BQ = 16;        // q rows per block
constexpr int NT = 512;       // 8 waves
constexpr int KC = 128;       // k per chunk (one 16-col tile per wave)
constexpr int QH_LD = 72;     // Qh row stride in f16
constexpr int SC_LD = 1032;   // sch row stride in f16
constexpr float LOG2E = 1.44269504f;

__device__ __forceinline__ float wred(float v) {
#pragma unroll
  for (int off = 32; off > 0; off >>= 1) v += __shfl_xor(v, off);
  return v;
}

__global__ __launch_bounds__(NT)
void fused_attn(const float* __restrict__ Q, const float* __restrict__ K,
                const float* __restrict__ V, const int* __restrict__ mask,
                const float* __restrict__ adj, const float* __restrict__ dist,
                const float* __restrict__ cw, const float* __restrict__ cb,
                float* __restrict__ outC, float* __restrict__ outA)
{
  __shared__ __align__(16) f16 Qh[BQ * QH_LD];     // 2.3 KB
  __shared__ __align__(16) f16 sch[BQ * SC_LD];    // 33.0 KB (C-scratch reuse)
  __shared__ float rs1w[8][16];
  __shared__ float rinv2[BQ];

  const int tid = threadIdx.x;
  // bijective XCD swizzle: 2048 blocks = 8 XCDs x 256 (4 heads per XCD)
  const int sw = (blockIdx.x & 7) * 256 + (blockIdx.x >> 3);
  const int qt = sw & 63;
  const int bh = sw >> 6;
  const int q0 = qt * BQ;
  const int wv = tid >> 6;    // wave 0..7
  const int ln = tid & 63;
  const int lg = ln >> 4;     // lane group 0..3
  const int li = ln & 15;

  const float* Qp = Q + ((size_t)bh * S_ + q0) * D_;
  const float* Kp = K + (size_t)bh * S_ * D_;
  const float* Vp = V + (size_t)bh * S_ * D_;
  const size_t rb = ((size_t)bh * S_ + q0) * S_;

  // stage Q tile -> f16
  if (tid < 256) {
    const int q = tid >> 4, c4 = (tid & 15) << 2;
    float4 v = *(const float4*)(Qp + q * D_ + c4);
    f16* d = &Qh[q * QH_LD + c4];
    d[0] = (f16)v.x; d[1] = (f16)v.y; d[2] = (f16)v.z; d[3] = (f16)v.w;
  }
  const float w0 = cw[0], w1 = cw[1], w2 = cw[2], bb = cb[0];
  __syncthreads();                                  // (1)

  // hoist Q fragments (A operand; lane li = q-row li, k = s*32 + lg*8)
  f16x8 aq0 = *(const f16x8*)&Qh[li * QH_LD + 0 * 32 + lg * 8];
  f16x8 aq1 = *(const f16x8*)&Qh[li * QH_LD + 1 * 32 + lg * 8];

  // ===== Phase A: UNMASKED e = exp(QK^T/8) via MFMA; K straight from global ==
  const int n0 = wv * 16;
  float rs[4] = {0.f, 0.f, 0.f, 0.f};
#pragma unroll 2
  for (int c = 0; c < 8; ++c) {
    const int kg = c * KC + n0 + li;
    const float* Kr = Kp + (size_t)kg * D_ + lg * 8;
    const float4 ka = *(const float4*)(Kr + 0);
    const float4 kb = *(const float4*)(Kr + 4);
    const float4 kc2 = *(const float4*)(Kr + 32);
    const float4 kd = *(const float4*)(Kr + 36);
    f16x8 b0, b1;
    b0[0] = (f16)ka.x; b0[1] = (f16)ka.y; b0[2] = (f16)ka.z; b0[3] = (f16)ka.w;
    b0[4] = (f16)kb.x; b0[5] = (f16)kb.y; b0[6] = (f16)kb.z; b0[7] = (f16)kb.w;
    b1[0] = (f16)kc2.x; b1[1] = (f16)kc2.y; b1[2] = (f16)kc2.z; b1[3] = (f16)kc2.w;
    b1[4] = (f16)kd.x; b1[5] = (f16)kd.y; b1[6] = (f16)kd.z; b1[7] = (f16)kd.w;
    f32x4 acc = {0.f, 0.f, 0.f, 0.f};
    acc = __builtin_amdgcn_mfma_f32_16x16x32_f16(aq0, b0, acc, 0, 0, 0);
    acc = __builtin_amdgcn_mfma_f32_16x16x32_f16(aq1, b1, acc, 0, 0, 0);
#pragma unroll
    for (int r = 0; r < 4; ++r) {            // D[m][n]: m=lg*4+r, n=li
      const int m = lg * 4 + r;
      const f16 ef = (f16)exp2f(acc[r] * (0.125f * LOG2E));
      sch[m * SC_LD + kg] = ef;
      rs[r] += (float)ef;                    // rounded full-row sum
    }
  }
#pragma unroll
  for (int r = 0; r < 4; ++r) {              // reduce over 16 lanes per group
    rs[r] += __shfl_xor(rs[r], 1); rs[r] += __shfl_xor(rs[r], 2);
    rs[r] += __shfl_xor(rs[r], 4); rs[r] += __shfl_xor(rs[r], 8);
  }
  if (li == 0) {
#pragma unroll
    for (int r = 0; r < 4; ++r) rs1w[wv][lg * 4 + r] = rs[r];
  }
  __syncthreads();                                  // (2) sch + rs1w visible

  // ===== Phase B: mask fold + conv-softmax; wave -> rows 2wv, 2wv+1 ==========
#pragma unroll
  for (int rr = 0; rr < 2; ++rr) {
    const int q = 2 * wv + rr;
    const size_t base = rb + (size_t)q * S_;
    const int k0 = ln * 4;
    // batched loads: all 12 global + 4 LDS issued before any use; the
    // sched_barrier(0) pins them (compiler may not sink past it).
    const int4 mv0 = *(const int4*)(mask + base + k0 + 0);
    const int4 mv1 = *(const int4*)(mask + base + k0 + 256);
    const int4 mv2 = *(const int4*)(mask + base + k0 + 512);
    const int4 mv3 = *(const int4*)(mask + base + k0 + 768);
    const float4 dv0 = *(const float4*)(dist + base + k0 + 0);
    const float4 dv1 = *(const float4*)(dist + base + k0 + 256);
    const float4 dv2 = *(const float4*)(dist + base + k0 + 512);
    const float4 dv3 = *(const float4*)(dist + base + k0 + 768);
    const float4 av0 = *(const float4*)(adj + base + k0 + 0);
    const float4 av1 = *(const float4*)(adj + base + k0 + 256);
    const float4 av2 = *(const float4*)(adj + base + k0 + 512);
    const float4 av3 = *(const float4*)(adj + base + k0 + 768);
    const f16x4 ef0 = *(const f16x4*)&sch[q * SC_LD + k0 + 0];
    const f16x4 ef1 = *(const f16x4*)&sch[q * SC_LD + k0 + 256];
    const f16x4 ef2 = *(const f16x4*)&sch[q * SC_LD + k0 + 512];
    const f16x4 ef3 = *(const f16x4*)&sch[q * SC_LD + k0 + 768];
    __builtin_amdgcn_sched_barrier(0);
    // denominator correction from masked entries
    float corr =
        (mv0.x ? (float)ef0[0] : 0.f) + (mv0.y ? (float)ef0[1] : 0.f) +
        (mv0.z ? (float)ef0[2] : 0.f) + (mv0.w ? (float)ef0[3] : 0.f) +
        (mv1.x ? (float)ef1[0] : 0.f) + (mv1.y ? (float)ef1[1] : 0.f) +
        (mv1.z ? (float)ef1[2] : 0.f) + (mv1.w ? (float)ef1[3] : 0.f) +
        (mv2.x ? (float)ef2[0] : 0.f) + (mv2.y ? (float)ef2[1] : 0.f) +
        (mv2.z ? (float)ef2[2] : 0.f) + (mv2.w ? (float)ef2[3] : 0.f) +
        (mv3.x ? (float)ef3[0] : 0.f) + (mv3.y ? (float)ef3[1] : 0.f) +
        (mv3.z ? (float)ef3[2] : 0.f) + (mv3.w ? (float)ef3[3] : 0.f);
    float tq = 0.f;
#pragma unroll
    for (int w = 0; w < 8; ++w) tq += rs1w[w][q];   // uniform broadcast reads
    corr = wred(corr);
    const float i1 = 1.f / (tq - corr);
    const float W0 = w0 * i1 * LOG2E, W1 = w1 * LOG2E, W2 = w2 * LOG2E;
    const float BBL = bb * LOG2E;
    f16x4 af0, af1, af2, af3;
    float s2 = 0.f;
#define CSM(AF, MV, DV, AV, EF)                                               \
    {                                                                         \
      const float t0 = fmaf(W0, (float)EF[0], fmaf(W1, DV.x, fmaf(W2, AV.x, BBL))); \
      const float t1 = fmaf(W0, (float)EF[1], fmaf(W1, DV.y, fmaf(W2, AV.y, BBL))); \
      const float t2 = fmaf(W0, (float)EF[2], fmaf(W1, DV.z, fmaf(W2, AV.z, BBL))); \
      const float t3 = fmaf(W0, (float)EF[3], fmaf(W1, DV.w, fmaf(W2, AV.w, BBL))); \
      const float a0 = MV.x ? 0.f : exp2f(t0);                                \
      const float a1 = MV.y ? 0.f : exp2f(t1);                                \
      const float a2 = MV.z ? 0.f : exp2f(t2);                                \
      const float a3 = MV.w ? 0.f : exp2f(t3);                                \
      AF[0] = (f16)a0; AF[1] = (f16)a1; AF[2] = (f16)a2; AF[3] = (f16)a3;     \
      s2 += a0 + a1 + a2 + a3;                                                \
    }
    CSM(af0, mv0, dv0, av0, ef0)
    CSM(af1, mv1, dv1, av1, ef1)
    CSM(af2, mv2, dv2, av2, ef2)
    CSM(af3, mv3, dv3, av3, ef3)
#undef CSM
    *(f16x4*)&sch[q * SC_LD + k0 + 0]   = af0;
    *(f16x4*)&sch[q * SC_LD + k0 + 256] = af1;
    *(f16x4*)&sch[q * SC_LD + k0 + 512] = af2;
    *(f16x4*)&sch[q * SC_LD + k0 + 768] = af3;
    s2 = wred(s2);
    const float i2 = 1.f / s2;
    if (ln == 0) rinv2[q] = i2;
    float4 o;
    o = make_float4((float)af0[0] * i2, (float)af0[1] * i2,
                    (float)af0[2] * i2, (float)af0[3] * i2);
    *(float4*)(outA + base + k0 + 0) = o;
    o = make_float4((float)af1[0] * i2, (float)af1[1] * i2,
                    (float)af1[2] * i2, (float)af1[3] * i2);
    *(float4*)(outA + base + k0 + 256) = o;
    o = make_float4((float)af2[0] * i2, (float)af2[1] * i2,
                    (float)af2[2] * i2, (float)af2[3] * i2);
    *(float4*)(outA + base + k0 + 512) = o;
    o = make_float4((float)af3[0] * i2, (float)af3[1] * i2,
                    (float)af3[2] * i2, (float)af3[3] * i2);
    *(float4*)(outA + base + k0 + 768) = o;
  }
  __syncthreads();                                  // (3) sch aw-values visible

  // ===== Phase C: ctx = P(f16) x V(f16); V^T fragments straight from global ==
  const int ntile = wv >> 1;
  const int spair = (wv & 1) * 2;
  const int d0 = ntile * 16 + li;
  f32x4 cacc = {0.f, 0.f, 0.f, 0.f};
#pragma unroll 2
  for (int c = 0; c < 8; ++c) {
#pragma unroll
    for (int u = 0; u < 2; ++u) {
      const int s = spair + u;
      const float* Vc = Vp + (size_t)(c * KC + s * 32 + lg * 8) * D_ + d0;
      f16x8 bfr;
#pragma unroll
      for (int j = 0; j < 8; ++j) bfr[j] = (f16)Vc[(size_t)j * D_];
      f16x8 a = *(const f16x8*)&sch[li * SC_LD + c * KC + s * 32 + lg * 8];
      cacc = __builtin_amdgcn_mfma_f32_16x16x32_f16(a, bfr, cacc, 0, 0, 0);
    }
  }
  __syncthreads();                                  // (4) all sch reads done
  float* fscr = reinterpret_cast<float*>(sch);      // alias 8 KB scratch
  *(f32x4*)&fscr[tid * 4] = cacc;
  __syncthreads();                                  // (5)
  if (tid < 256) {                    // combine wave pairs, scale, write ctx
    const int t = tid >> 6, l2 = tid & 63;
    const int g2 = l2 >> 4, n = l2 & 15;
    f32x4 p  = *(const f32x4*)&fscr[((2 * t) * 64 + l2) * 4];
    f32x4 p2 = *(const f32x4*)&fscr[((2 * t + 1) * 64 + l2) * 4];
#pragma unroll
    for (int r = 0; r < 4; ++r) {
      const int m = g2 * 4 + r;
      outC[((size_t)bh * S_ + q0 + m) * D_ + t * 16 + n] = (p[r] + p2[r]) * rinv2[m];
    }
  }
}

extern "C" void kernel_launch(void* const* d_in, const int* in_sizes, int n_in,
                              void* d_out, int out_size, void* d_ws, size_t ws_size,
                              hipStream_t stream) {
  const float* Q    = (const float*)d_in[0];
  const float* K    = (const float*)d_in[1];
  const float* V    = (const float*)d_in[2];
  const int*   mask = (const int*)  d_in[3];
  const float* adj  = (const float*)d_in[4];
  const float* dist = (const float*)d_in[5];
  const float* cw   = (const float*)d_in[6];
  const float* cb   = (const float*)d_in[7];

  float* outC = (float*)d_out;                                   // [B,H,S,D]
  float* outA = outC + (size_t)B_ * H_ * S_ * D_;                // [B,H,S,S]

  fused_attn<<<dim3(B_ * H_ * (S_ / BQ)), NT, 0, stream>>>(
      Q, K, V, mask, adj, dist, cw, cb, outC, outA);
}

// Round 13
// 141.896 us; speedup vs baseline: 1.2656x; 1.2092x over previous
//
#include <hip/hip_runtime.h>

// Fused double-softmax attention, fp32 in/out, f16 MFMA for QK^T and PV.
// B=4 H=8 S=1024 D=64. Outputs: context [B,H,S,D] then attn [B,H,S,S].
// R13 = R12 + NONTEMPORAL hints on all streaming traffic (mask/dist/adj
// loads, outA stores) so the once-read streams stop evicting K/V from L2.
typedef _Float16 f16;
typedef _Float16 f16x8 __attribute__((ext_vector_type(8)));
typedef _Float16 f16x4 __attribute__((ext_vector_type(4)));
typedef float f32x4 __attribute__((ext_vector_type(4)));
typedef int   i32x4 __attribute__((ext_vector_type(4)));

constexpr int B_ = 4, H_ = 8, S_ = 1024, D_ = 64;
constexpr int BQ = 16;        // q rows per block
constexpr int NT = 512;       // 8 waves
constexpr int KC = 128;       // k per chunk (one 16-col tile per wave)
constexpr int QH_LD = 72;     // Qh row stride in f16
constexpr int SC_LD = 1032;   // sch row stride in f16
constexpr float LOG2E = 1.44269504f;

__device__ __forceinline__ float wred(float v) {
#pragma unroll
  for (int off = 32; off > 0; off >>= 1) v += __shfl_xor(v, off);
  return v;
}

__global__ __launch_bounds__(NT)
void fused_attn(const float* __restrict__ Q, const float* __restrict__ K,
                const float* __restrict__ V, const int* __restrict__ mask,
                const float* __restrict__ adj, const float* __restrict__ dist,
                const float* __restrict__ cw, const float* __restrict__ cb,
                float* __restrict__ outC, float* __restrict__ outA)
{
  __shared__ __align__(16) f16 Qh[BQ * QH_LD];     // 2.3 KB
  __shared__ __align__(16) f16 sch[BQ * SC_LD];    // 33.0 KB (C-scratch reuse)
  __shared__ float rs1w[8][16];
  __shared__ float rinv2[BQ];

  const int tid = threadIdx.x;
  // bijective XCD swizzle: 2048 blocks = 8 XCDs x 256 (4 heads per XCD)
  const int sw = (blockIdx.x & 7) * 256 + (blockIdx.x >> 3);
  const int qt = sw & 63;
  const int bh = sw >> 6;
  const int q0 = qt * BQ;
  const int wv = tid >> 6;    // wave 0..7
  const int ln = tid & 63;
  const int lg = ln >> 4;     // lane group 0..3
  const int li = ln & 15;

  const float* Qp = Q + ((size_t)bh * S_ + q0) * D_;
  const float* Kp = K + (size_t)bh * S_ * D_;
  const float* Vp = V + (size_t)bh * S_ * D_;
  const size_t rb = ((size_t)bh * S_ + q0) * S_;

  // stage Q tile -> f16
  if (tid < 256) {
    const int q = tid >> 4, c4 = (tid & 15) << 2;
    float4 v = *(const float4*)(Qp + q * D_ + c4);
    f16* d = &Qh[q * QH_LD + c4];
    d[0] = (f16)v.x; d[1] = (f16)v.y; d[2] = (f16)v.z; d[3] = (f16)v.w;
  }
  const float w0 = cw[0], w1 = cw[1], w2 = cw[2], bb = cb[0];
  __syncthreads();                                  // (1)

  // hoist Q fragments (A operand; lane li = q-row li, k = s*32 + lg*8)
  f16x8 aq0 = *(const f16x8*)&Qh[li * QH_LD + 0 * 32 + lg * 8];
  f16x8 aq1 = *(const f16x8*)&Qh[li * QH_LD + 1 * 32 + lg * 8];

  // ===== Phase A: UNMASKED e = exp(QK^T/8) via MFMA; K straight from global ==
  const int n0 = wv * 16;
  float rs[4] = {0.f, 0.f, 0.f, 0.f};
#pragma unroll 2
  for (int c = 0; c < 8; ++c) {
    const int kg = c * KC + n0 + li;
    const float* Kr = Kp + (size_t)kg * D_ + lg * 8;
    const float4 ka = *(const float4*)(Kr + 0);
    const float4 kb = *(const float4*)(Kr + 4);
    const float4 kc2 = *(const float4*)(Kr + 32);
    const float4 kd = *(const float4*)(Kr + 36);
    f16x8 b0, b1;
    b0[0] = (f16)ka.x; b0[1] = (f16)ka.y; b0[2] = (f16)ka.z; b0[3] = (f16)ka.w;
    b0[4] = (f16)kb.x; b0[5] = (f16)kb.y; b0[6] = (f16)kb.z; b0[7] = (f16)kb.w;
    b1[0] = (f16)kc2.x; b1[1] = (f16)kc2.y; b1[2] = (f16)kc2.z; b1[3] = (f16)kc2.w;
    b1[4] = (f16)kd.x; b1[5] = (f16)kd.y; b1[6] = (f16)kd.z; b1[7] = (f16)kd.w;
    f32x4 acc = {0.f, 0.f, 0.f, 0.f};
    acc = __builtin_amdgcn_mfma_f32_16x16x32_f16(aq0, b0, acc, 0, 0, 0);
    acc = __builtin_amdgcn_mfma_f32_16x16x32_f16(aq1, b1, acc, 0, 0, 0);
#pragma unroll
    for (int r = 0; r < 4; ++r) {            // D[m][n]: m=lg*4+r, n=li
      const int m = lg * 4 + r;
      const f16 ef = (f16)exp2f(acc[r] * (0.125f * LOG2E));
      sch[m * SC_LD + kg] = ef;
      rs[r] += (float)ef;                    // rounded full-row sum
    }
  }
#pragma unroll
  for (int r = 0; r < 4; ++r) {              // reduce over 16 lanes per group
    rs[r] += __shfl_xor(rs[r], 1); rs[r] += __shfl_xor(rs[r], 2);
    rs[r] += __shfl_xor(rs[r], 4); rs[r] += __shfl_xor(rs[r], 8);
  }
  if (li == 0) {
#pragma unroll
    for (int r = 0; r < 4; ++r) rs1w[wv][lg * 4 + r] = rs[r];
  }
  __syncthreads();                                  // (2) sch + rs1w visible

  // ===== Phase B: mask fold + conv-softmax; wave -> rows 2wv, 2wv+1 ==========
#pragma unroll
  for (int rr = 0; rr < 2; ++rr) {
    const int q = 2 * wv + rr;
    const size_t base = rb + (size_t)q * S_;
    const int k0 = ln * 4;
    // batched NONTEMPORAL loads: 12 global + 4 LDS issued before any use
    const i32x4 mv0 = __builtin_nontemporal_load((const i32x4*)(mask + base + k0 + 0));
    const i32x4 mv1 = __builtin_nontemporal_load((const i32x4*)(mask + base + k0 + 256));
    const i32x4 mv2 = __builtin_nontemporal_load((const i32x4*)(mask + base + k0 + 512));
    const i32x4 mv3 = __builtin_nontemporal_load((const i32x4*)(mask + base + k0 + 768));
    const f32x4 dv0 = __builtin_nontemporal_load((const f32x4*)(dist + base + k0 + 0));
    const f32x4 dv1 = __builtin_nontemporal_load((const f32x4*)(dist + base + k0 + 256));
    const f32x4 dv2 = __builtin_nontemporal_load((const f32x4*)(dist + base + k0 + 512));
    const f32x4 dv3 = __builtin_nontemporal_load((const f32x4*)(dist + base + k0 + 768));
    const f32x4 av0 = __builtin_nontemporal_load((const f32x4*)(adj + base + k0 + 0));
    const f32x4 av1 = __builtin_nontemporal_load((const f32x4*)(adj + base + k0 + 256));
    const f32x4 av2 = __builtin_nontemporal_load((const f32x4*)(adj + base + k0 + 512));
    const f32x4 av3 = __builtin_nontemporal_load((const f32x4*)(adj + base + k0 + 768));
    const f16x4 ef0 = *(const f16x4*)&sch[q * SC_LD + k0 + 0];
    const f16x4 ef1 = *(const f16x4*)&sch[q * SC_LD + k0 + 256];
    const f16x4 ef2 = *(const f16x4*)&sch[q * SC_LD + k0 + 512];
    const f16x4 ef3 = *(const f16x4*)&sch[q * SC_LD + k0 + 768];
    __builtin_amdgcn_sched_barrier(0);
    // denominator correction from masked entries
    float corr =
        (mv0[0] ? (float)ef0[0] : 0.f) + (mv0[1] ? (float)ef0[1] : 0.f) +
        (mv0[2] ? (float)ef0[2] : 0.f) + (mv0[3] ? (float)ef0[3] : 0.f) +
        (mv1[0] ? (float)ef1[0] : 0.f) + (mv1[1] ? (float)ef1[1] : 0.f) +
        (mv1[2] ? (float)ef1[2] : 0.f) + (mv1[3] ? (float)ef1[3] : 0.f) +
        (mv2[0] ? (float)ef2[0] : 0.f) + (mv2[1] ? (float)ef2[1] : 0.f) +
        (mv2[2] ? (float)ef2[2] : 0.f) + (mv2[3] ? (float)ef2[3] : 0.f) +
        (mv3[0] ? (float)ef3[0] : 0.f) + (mv3[1] ? (float)ef3[1] : 0.f) +
        (mv3[2] ? (float)ef3[2] : 0.f) + (mv3[3] ? (float)ef3[3] : 0.f);
    float tq = 0.f;
#pragma unroll
    for (int w = 0; w < 8; ++w) tq += rs1w[w][q];   // uniform broadcast reads
    corr = wred(corr);
    const float i1 = 1.f / (tq - corr);
    const float W0 = w0 * i1 * LOG2E, W1 = w1 * LOG2E, W2 = w2 * LOG2E;
    const float BBL = bb * LOG2E;
    f16x4 af0, af1, af2, af3;
    float s2 = 0.f;
#define CSM(AF, MV, DV, AV, EF)                                               \
    {                                                                         \
      const float t0 = fmaf(W0, (float)EF[0], fmaf(W1, DV[0], fmaf(W2, AV[0], BBL))); \
      const float t1 = fmaf(W0, (float)EF[1], fmaf(W1, DV[1], fmaf(W2, AV[1], BBL))); \
      const float t2 = fmaf(W0, (float)EF[2], fmaf(W1, DV[2], fmaf(W2, AV[2], BBL))); \
      const float t3 = fmaf(W0, (float)EF[3], fmaf(W1, DV[3], fmaf(W2, AV[3], BBL))); \
      const float a0 = MV[0] ? 0.f : exp2f(t0);                               \
      const float a1 = MV[1] ? 0.f : exp2f(t1);                               \
      const float a2 = MV[2] ? 0.f : exp2f(t2);                               \
      const float a3 = MV[3] ? 0.f : exp2f(t3);                               \
      AF[0] = (f16)a0; AF[1] = (f16)a1; AF[2] = (f16)a2; AF[3] = (f16)a3;     \
      s2 += a0 + a1 + a2 + a3;                                                \
    }
    CSM(af0, mv0, dv0, av0, ef0)
    CSM(af1, mv1, dv1, av1, ef1)
    CSM(af2, mv2, dv2, av2, ef2)
    CSM(af3, mv3, dv3, av3, ef3)
#undef CSM
    *(f16x4*)&sch[q * SC_LD + k0 + 0]   = af0;
    *(f16x4*)&sch[q * SC_LD + k0 + 256] = af1;
    *(f16x4*)&sch[q * SC_LD + k0 + 512] = af2;
    *(f16x4*)&sch[q * SC_LD + k0 + 768] = af3;
    s2 = wred(s2);
    const float i2 = 1.f / s2;
    if (ln == 0) rinv2[q] = i2;
    f32x4 o;
    o[0] = (float)af0[0] * i2; o[1] = (float)af0[1] * i2;
    o[2] = (float)af0[2] * i2; o[3] = (float)af0[3] * i2;
    __builtin_nontemporal_store(o, (f32x4*)(outA + base + k0 + 0));
    o[0] = (float)af1[0] * i2; o[1] = (float)af1[1] * i2;
    o[2] = (float)af1[2] * i2; o[3] = (float)af1[3] * i2;
    __builtin_nontemporal_store(o, (f32x4*)(outA + base + k0 + 256));
    o[0] = (float)af2[0] * i2; o[1] = (float)af2[1] * i2;
    o[2] = (float)af2[2] * i2; o[3] = (float)af2[3] * i2;
    __builtin_nontemporal_store(o, (f32x4*)(outA + base + k0 + 512));
    o[0] = (float)af3[0] * i2; o[1] = (float)af3[1] * i2;
    o[2] = (float)af3[2] * i2; o[3] = (float)af3[3] * i2;
    __builtin_nontemporal_store(o, (f32x4*)(outA + base + k0 + 768));
  }
  __syncthreads();                                  // (3) sch aw-values visible

  // ===== Phase C: ctx = P(f16) x V(f16); V^T fragments straight from global ==
  const int ntile = wv >> 1;
  const int spair = (wv & 1) * 2;
  const int d0 = ntile * 16 + li;
  f32x4 cacc = {0.f, 0.f, 0.f, 0.f};
#pragma unroll 2
  for (int c = 0; c < 8; ++c) {
#pragma unroll
    for (int u = 0; u < 2; ++u) {
      const int s = spair + u;
      const float* Vc = Vp + (size_t)(c * KC + s * 32 + lg * 8) * D_ + d0;
      f16x8 bfr;
#pragma unroll
      for (int j = 0; j < 8; ++j) bfr[j] = (f16)Vc[(size_t)j * D_];
      f16x8 a = *(const f16x8*)&sch[li * SC_LD + c * KC + s * 32 + lg * 8];
      cacc = __builtin_amdgcn_mfma_f32_16x16x32_f16(a, bfr, cacc, 0, 0, 0);
    }
  }
  __syncthreads();                                  // (4) all sch reads done
  float* fscr = reinterpret_cast<float*>(sch);      // alias 8 KB scratch
  *(f32x4*)&fscr[tid * 4] = cacc;
  __syncthreads();                                  // (5)
  if (tid < 256) {                    // combine wave pairs, scale, write ctx
    const int t = tid >> 6, l2 = tid & 63;
    const int g2 = l2 >> 4, n = l2 & 15;
    f32x4 p  = *(const f32x4*)&fscr[((2 * t) * 64 + l2) * 4];
    f32x4 p2 = *(const f32x4*)&fscr[((2 * t + 1) * 64 + l2) * 4];
#pragma unroll
    for (int r = 0; r < 4; ++r) {
      const int m = g2 * 4 + r;
      outC[((size_t)bh * S_ + q0 + m) * D_ + t * 16 + n] = (p[r] + p2[r]) * rinv2[m];
    }
  }
}

extern "C" void kernel_launch(void* const* d_in, const int* in_sizes, int n_in,
                              void* d_out, int out_size, void* d_ws, size_t ws_size,
                              hipStream_t stream) {
  const float* Q    = (const float*)d_in[0];
  const float* K    = (const float*)d_in[1];
  const float* V    = (const float*)d_in[2];
  const int*   mask = (const int*)  d_in[3];
  const float* adj  = (const float*)d_in[4];
  const float* dist = (const float*)d_in[5];
  const float* cw   = (const float*)d_in[6];
  const float* cb   = (const float*)d_in[7];

  float* outC = (float*)d_out;                                   // [B,H,S,D]
  float* outA = outC + (size_t)B_ * H_ * S_ * D_;                // [B,H,S,S]

  fused_attn<<<dim3(B_ * H_ * (S_ / BQ)), NT, 0, stream>>>(
      Q, K, V, mask, adj, dist, cw, cb, outC, outA);
}